// Round 8
// baseline (487.236 us; speedup 1.0000x reference)
//
#include <hip/hip_runtime.h>
#include <hip/hip_bf16.h>
#include <cstddef>

// ---------------------------------------------------------------------------
// GNN layer (RED-GNN style), MI355X — round 8.
// vs round 7 (367 us = node 185 + ~180 of small serialized passes):
//  * fused_pre: hsWs matmul + Br/Cq precompute + obj-hist + out_obj in ONE
//    launch (block-range partitioned) — 3 launches -> 1, fewer graph bubbles.
//  * node_kernel: 8-edge unroll (16-int meta read, 10 row gathers in flight,
//    two independent reduce chains interleaved) to double MLP; counters said
//    latency/BW mixed-bound at 36% VALU / 44% HBM.
// Pipeline: memset(cnt) | fused_pre | scan x3 | scatter(int2) | node_kernel
// Packing: meta = int2{ (rel<<17)|sub , (e<<8)|r_idx }.
// ---------------------------------------------------------------------------

typedef float f32x4 __attribute__((ext_vector_type(4)));

static __device__ __forceinline__ void nt_store4(float* p, float4 v) {
    f32x4 t = {v.x, v.y, v.z, v.w};
    __builtin_nontemporal_store(t, (f32x4*)p);
}
#define NT_STORE(p, v) __builtin_nontemporal_store((v), (p))

// Fused prologue. Block ranges:
//   [0, mmB)            : hsWs = hidden @ Ws   (grid-stride, 4 rows/block)
//   [mmB, mmB+relB)     : Br = rela@Wr ; Cq = rela[q_rel]@Wqr + b
//   [mmB+relB, ...)     : obj histogram + out_obj NT write
__global__ void fused_pre_kernel(const float* __restrict__ hidden,
                                 const float* __restrict__ Ws,
                                 float* __restrict__ hsWs, int nnode,
                                 const float* __restrict__ rela,
                                 const float* __restrict__ Wr,
                                 const float* __restrict__ Wqr,
                                 const float* __restrict__ Wqr_b,
                                 const int* __restrict__ q_rel,
                                 float* __restrict__ Br,
                                 float* __restrict__ Cq, int nrel, int nq,
                                 const int* __restrict__ edges,
                                 int* __restrict__ cnt_obj,
                                 float* __restrict__ out_obj, int nedge,
                                 int mmB, int relB) {
    __shared__ float W1[64][64];
    __shared__ float W2[64][64];
    int bid = blockIdx.x;
    int tid = threadIdx.x;

    if (bid < mmB) {
        for (int i = tid; i < 4096; i += 256) W1[i >> 6][i & 63] = Ws[i];
        __syncthreads();
        int col = tid & 63, r4 = tid >> 6;
        for (long row = (long)bid * 4 + r4; row < nnode; row += (long)mmB * 4) {
            float xv  = hidden[row * 64 + col];
            float acc = 0.0f;
#pragma unroll
            for (int k = 0; k < 64; ++k)
                acc = fmaf(__shfl(xv, k, 64), W1[k][col], acc);
            hsWs[row * 64 + col] = acc;
        }
    } else if (bid < mmB + relB) {
        for (int i = tid; i < 4096; i += 256) {
            W1[i >> 6][i & 63] = Wr[i];
            W2[i >> 6][i & 63] = Wqr[i];
        }
        __syncthreads();
        int col = tid & 63, r4 = tid >> 6;
        int row = (bid - mmB) * 4 + r4;
        int total = nrel + nq;
        if (row < total) {
            if (row < nrel) {
                float xv  = rela[(size_t)row * 64 + col];
                float acc = 0.0f;
#pragma unroll
                for (int k = 0; k < 64; ++k)
                    acc = fmaf(__shfl(xv, k, 64), W1[k][col], acc);
                Br[(size_t)row * 64 + col] = acc;
            } else {
                int q  = row - nrel;
                int rr = q_rel[q];
                float xv  = rela[(size_t)rr * 64 + col];
                float acc = Wqr_b[col];
#pragma unroll
                for (int k = 0; k < 64; ++k)
                    acc = fmaf(__shfl(xv, k, 64), W2[k][col], acc);
                Cq[(size_t)q * 64 + col] = acc;
            }
        }
    } else {
        int e = (bid - mmB - relB) * 256 + tid;
        if (e < nedge) {
            int obj = edges[(size_t)e * 6 + 5];
            atomicAdd(&cnt_obj[obj], 1);
            NT_STORE(&out_obj[e], (float)obj);
        }
    }
}

// ---- 3-pass exclusive scan over cnt[n], chunk = 1024 ----

__global__ void scan_reduce_kernel(const int* __restrict__ cnt,
                                   int* __restrict__ bsum, int n) {
    int i = blockIdx.x * 1024 + threadIdx.x;
    int v = (i < n) ? cnt[i] : 0;
    int lane = threadIdx.x & 63, w = threadIdx.x >> 6;
#pragma unroll
    for (int m = 1; m < 64; m <<= 1) v += __shfl_xor(v, m, 64);
    __shared__ int ws[16];
    if (lane == 0) ws[w] = v;
    __syncthreads();
    if (threadIdx.x == 0) {
        int s = 0;
#pragma unroll
        for (int k = 0; k < 16; ++k) s += ws[k];
        bsum[blockIdx.x] = s;
    }
}

__global__ void scan_top_kernel(int* __restrict__ bsum, int nb) {
    int tid = threadIdx.x;
    int lane = tid & 63, w = tid >> 6;
    int v = (tid < nb) ? bsum[tid] : 0;
    int ins = v;
#pragma unroll
    for (int off = 1; off < 64; off <<= 1) {
        int t = __shfl_up(ins, off, 64);
        if (lane >= off) ins += t;
    }
    __shared__ int ws[16];
    __shared__ int wo[16];
    if (lane == 63) ws[w] = ins;
    __syncthreads();
    if (tid == 0) {
        int s = 0;
        for (int k = 0; k < 16; ++k) { wo[k] = s; s += ws[k]; }
    }
    __syncthreads();
    if (tid < nb) bsum[tid] = wo[w] + ins - v;   // exclusive
}

__global__ void scan_apply_kernel(const int* __restrict__ cnt,
                                  const int* __restrict__ boffs,
                                  int* __restrict__ out1,
                                  int* __restrict__ out2, int n) {
    int i = blockIdx.x * 1024 + threadIdx.x;
    int lane = threadIdx.x & 63, w = threadIdx.x >> 6;
    int v = (i < n) ? cnt[i] : 0;
    int ins = v;
#pragma unroll
    for (int off = 1; off < 64; off <<= 1) {
        int t = __shfl_up(ins, off, 64);
        if (lane >= off) ins += t;
    }
    __shared__ int ws[16];
    __shared__ int wo[16];
    if (lane == 63) ws[w] = ins;
    __syncthreads();
    if (threadIdx.x == 0) {
        int s = 0;
        for (int k = 0; k < 16; ++k) { wo[k] = s; s += ws[k]; }
    }
    __syncthreads();
    if (i < n) {
        int r = boffs[blockIdx.x] + wo[w] + ins - v;
        out1[i] = r;
        if (out2) out2[i] = r;
    }
}

// Counting-sort scatter: ONE packed int2 write per edge.
__global__ void scatter_kernel(const int* __restrict__ edges,
                               int* __restrict__ cur_obj,
                               int2* __restrict__ meta, int nedge) {
    int e = blockIdx.x * 256 + threadIdx.x;
    if (e >= nedge) return;
    int r_idx = edges[(size_t)e * 6 + 0];
    int rel   = edges[(size_t)e * 6 + 2];
    int sub   = edges[(size_t)e * 6 + 4];
    int obj   = edges[(size_t)e * 6 + 5];
    int p = atomicAdd(&cur_obj[obj], 1);
    meta[p] = make_int2((rel << 17) | sub, (e << 8) | r_idx);
}

// Merged per-node kernel, 8-edge unrolled.
// One wave per node; 16 lanes x float4 per edge; 2x4 edges in flight.
__global__ void node_kernel(const int2* __restrict__ meta,
                            const float* __restrict__ hsWs,
                            const float* __restrict__ hidden,
                            const float* __restrict__ rela,
                            const float* __restrict__ Br,
                            const float* __restrict__ Cq,
                            const float* __restrict__ w_alpha_w,
                            const float* __restrict__ w_alpha_b,
                            const int* __restrict__ offs,
                            const int* __restrict__ cnt,
                            const float* __restrict__ Wh,
                            float* __restrict__ out_alpha,
                            float* __restrict__ out_message,
                            float* __restrict__ out_alpha_temp,
                            float* __restrict__ hidden_new,
                            int nnode, int nedge) {
    __shared__ float Wl[64][64];
    int tid = threadIdx.x;
    for (int i = tid; i < 4096; i += 256) Wl[i >> 6][i & 63] = Wh[i];
    __syncthreads();
    int lane = tid & 63;
    int g    = lane >> 4;        // edge slot (0..3)
    int s    = lane & 15;        // feature chunk (4 floats)
    int wv   = tid >> 6;
    const float4 wa = *(const float4*)(w_alpha_w + s * 4);
    const float  wb = w_alpha_b[0];

    for (long node = (long)blockIdx.x * 4 + wv; node < nnode;
         node += (long)gridDim.x * 4) {
        int beg = offs[node];
        int num = cnt[node];
        int end = beg + num;
        float4 acc = make_float4(0.f, 0.f, 0.f, 0.f);

        for (int p0 = beg; p0 < end; p0 += 8) {
            // 8 positions' packed meta = 16 consecutive ints (linear read).
            int mi = 0;
            long mofs = (long)p0 * 2 + lane;
            if (lane < 16 && mofs < (long)nedge * 2)
                mi = ((const int*)meta)[mofs];
            int A0 = __shfl(mi, g * 2 + 0, 64);
            int B0 = __shfl(mi, g * 2 + 1, 64);
            int A1 = __shfl(mi, 8 + g * 2 + 0, 64);
            int B1 = __shfl(mi, 8 + g * 2 + 1, 64);
            bool v0 = (p0 + g < end);
            bool v1 = (p0 + 4 + g < end);
            int sub0 = v0 ? (A0 & 0x1FFFF) : 0;
            int rel0 = v0 ? ((A0 >> 17) & 0x1FF) : 0;
            int ri0  = v0 ? (B0 & 255) : 0;
            long e0  = ((unsigned)B0) >> 8;
            int sub1 = v1 ? (A1 & 0x1FFFF) : 0;
            int rel1 = v1 ? ((A1 >> 17) & 0x1FF) : 0;
            int ri1  = v1 ? (B1 & 255) : 0;
            long e1  = ((unsigned)B1) >> 8;

            // Issue all 10 row gathers before consuming.
            const float4 h40 = *(const float4*)(hsWs + (size_t)sub0 * 64 + s * 4);
            const float4 b40 = *(const float4*)(Br   + (size_t)rel0 * 64 + s * 4);
            const float4 c40 = *(const float4*)(Cq   + (size_t)ri0  * 64 + s * 4);
            const float4 hv0 = *(const float4*)(hidden + (size_t)sub0 * 64 + s * 4);
            const float4 rv0 = *(const float4*)(rela   + (size_t)rel0 * 64 + s * 4);
            const float4 h41 = *(const float4*)(hsWs + (size_t)sub1 * 64 + s * 4);
            const float4 b41 = *(const float4*)(Br   + (size_t)rel1 * 64 + s * 4);
            const float4 c41 = *(const float4*)(Cq   + (size_t)ri1  * 64 + s * 4);
            const float4 hv1 = *(const float4*)(hidden + (size_t)sub1 * 64 + s * 4);
            const float4 rv1 = *(const float4*)(rela   + (size_t)rel1 * 64 + s * 4);

            float4 a0, a1;
            a0.x = fmaxf(h40.x + b40.x + c40.x, 0.0f);
            a0.y = fmaxf(h40.y + b40.y + c40.y, 0.0f);
            a0.z = fmaxf(h40.z + b40.z + c40.z, 0.0f);
            a0.w = fmaxf(h40.w + b40.w + c40.w, 0.0f);
            a1.x = fmaxf(h41.x + b41.x + c41.x, 0.0f);
            a1.y = fmaxf(h41.y + b41.y + c41.y, 0.0f);
            a1.z = fmaxf(h41.z + b41.z + c41.z, 0.0f);
            a1.w = fmaxf(h41.w + b41.w + c41.w, 0.0f);

            float p0d = a0.x * wa.x + a0.y * wa.y + a0.z * wa.z + a0.w * wa.w;
            float p1d = a1.x * wa.x + a1.y * wa.y + a1.z * wa.z + a1.w * wa.w;
            // two independent 4-step reduce chains, interleaved
            p0d += __shfl_xor(p0d, 1, 64);  p1d += __shfl_xor(p1d, 1, 64);
            p0d += __shfl_xor(p0d, 2, 64);  p1d += __shfl_xor(p1d, 2, 64);
            p0d += __shfl_xor(p0d, 4, 64);  p1d += __shfl_xor(p1d, 4, 64);
            p0d += __shfl_xor(p0d, 8, 64);  p1d += __shfl_xor(p1d, 8, 64);

            float at0 = p0d + wb;
            float at1 = p1d + wb;
            float al0 = v0 ? 1.0f / (1.0f + __expf(-at0)) : 0.0f;
            float al1 = v1 ? 1.0f / (1.0f + __expf(-at1)) : 0.0f;

            float4 m0, m1;
            m0.x = al0 * (hv0.x + rv0.x); m0.y = al0 * (hv0.y + rv0.y);
            m0.z = al0 * (hv0.z + rv0.z); m0.w = al0 * (hv0.w + rv0.w);
            m1.x = al1 * (hv1.x + rv1.x); m1.y = al1 * (hv1.y + rv1.y);
            m1.z = al1 * (hv1.z + rv1.z); m1.w = al1 * (hv1.w + rv1.w);

            acc.x += m0.x + m1.x; acc.y += m0.y + m1.y;
            acc.z += m0.z + m1.z; acc.w += m0.w + m1.w;

            if (v0) {
                nt_store4(out_message + e0 * 64 + s * 4, m0);
                if (s == 0) { out_alpha[e0] = al0; out_alpha_temp[e0] = at0; }
            }
            if (v1) {
                nt_store4(out_message + e1 * 64 + s * 4, m1);
                if (s == 0) { out_alpha[e1] = al1; out_alpha_temp[e1] = at1; }
            }
        }

        // reduce across the 4 groups; all lanes end with the full row sum
        acc.x += __shfl_xor(acc.x, 16, 64); acc.x += __shfl_xor(acc.x, 32, 64);
        acc.y += __shfl_xor(acc.y, 16, 64); acc.y += __shfl_xor(acc.y, 32, 64);
        acc.z += __shfl_xor(acc.z, 16, 64); acc.z += __shfl_xor(acc.z, 32, 64);
        acc.w += __shfl_xor(acc.w, 16, 64); acc.w += __shfl_xor(acc.w, 32, 64);

        // matvec: out[lane] = sum_k x_k * Wl[k][lane]
        float outv = 0.0f;
#pragma unroll
        for (int k = 0; k < 64; ++k) {
            float xk;
            if      ((k & 3) == 0) xk = __shfl(acc.x, k >> 2, 64);
            else if ((k & 3) == 1) xk = __shfl(acc.y, k >> 2, 64);
            else if ((k & 3) == 2) xk = __shfl(acc.z, k >> 2, 64);
            else                   xk = __shfl(acc.w, k >> 2, 64);
            outv = fmaf(xk, Wl[k][lane], outv);
        }
        NT_STORE(&hidden_new[node * 64 + lane], outv);
    }
}

extern "C" void kernel_launch(void* const* d_in, const int* in_sizes, int n_in,
                              void* d_out, int out_size, void* d_ws, size_t ws_size,
                              hipStream_t stream) {
    const int*   q_rel     = (const int*)d_in[1];
    const float* hidden    = (const float*)d_in[2];
    const int*   edges     = (const int*)d_in[3];
    const float* rela      = (const float*)d_in[5];
    const float* Ws        = (const float*)d_in[6];
    const float* Wr        = (const float*)d_in[7];
    const float* Wqr       = (const float*)d_in[8];
    const float* Wqr_b     = (const float*)d_in[9];
    const float* w_alpha_w = (const float*)d_in[10];
    const float* w_alpha_b = (const float*)d_in[11];
    const float* W_h       = (const float*)d_in[12];

    const int n_node = in_sizes[2] / 64;    // 100000
    const int n_edge = in_sizes[3] / 6;     // 1000000
    const int n_rel  = in_sizes[5] / 64;    // 401
    const int n_q    = in_sizes[1];         // 256

    // Output layout (all fp32, return order).
    float* out            = (float*)d_out;
    float* out_hidden_new = out;
    float* out_alpha      = out + (size_t)n_node * 64;
    float* out_message    = out_alpha + n_edge;
    float* out_obj        = out_message + (size_t)n_edge * 64;
    float* out_alpha_temp = out_obj + n_edge;

    // Workspace layout (~35 MB).
    float* hsWs    = (float*)d_ws;                       // n_node*64
    float* Br      = hsWs + (size_t)n_node * 64;         // n_rel*64
    float* Cq      = Br + (size_t)n_rel * 64;            // n_q*64
    int*   cnt_obj = (int*)(Cq + (size_t)n_q * 64);      // n_node
    int*   offs_obj= cnt_obj + n_node;                   // n_node
    int*   cur_obj = offs_obj + n_node;                  // n_node
    int*   bsum    = cur_obj + n_node;                   // 1024
    int2*  meta    = (int2*)(bsum + 1024);               // n_edge int2 (8 MB)

    const int nb = (n_node + 1023) / 1024;               // scan blocks (98)

    (void)hipMemsetAsync(cnt_obj, 0, (size_t)n_node * sizeof(int), stream);

    // 1) fused prologue: hsWs matmul | Br,Cq | obj hist + out_obj
    const int mmB   = 2048;
    const int relB  = (n_rel + n_q + 3) / 4;
    const int histB = (n_edge + 255) / 256;
    fused_pre_kernel<<<mmB + relB + histB, 256, 0, stream>>>(
        hidden, Ws, hsWs, n_node,
        rela, Wr, Wqr, Wqr_b, q_rel, Br, Cq, n_rel, n_q,
        edges, cnt_obj, out_obj, n_edge, mmB, relB);

    // 2) exclusive scan: cnt_obj -> offs_obj (+ cur_obj cursor copy)
    scan_reduce_kernel<<<nb, 1024, 0, stream>>>(cnt_obj, bsum, n_node);
    scan_top_kernel<<<1, 1024, 0, stream>>>(bsum, nb);
    scan_apply_kernel<<<nb, 1024, 0, stream>>>(cnt_obj, bsum, offs_obj,
                                               cur_obj, n_node);

    // 3) counting-sort scatter (one int2 per edge)
    scatter_kernel<<<(n_edge + 255) / 256, 256, 0, stream>>>(edges, cur_obj,
                                                             meta, n_edge);

    // 4) merged per-node kernel: per-edge compute + aggregate + @W_h
    node_kernel<<<4096, 256, 0, stream>>>(meta, hsWs, hidden, rela, Br, Cq,
                                          w_alpha_w, w_alpha_b,
                                          offs_obj, cnt_obj, W_h,
                                          out_alpha, out_message,
                                          out_alpha_temp, out_hidden_new,
                                          n_node, n_edge);
}

// Round 9
// 359.676 us; speedup vs baseline: 1.3547x; 1.3547x over previous
//
#include <hip/hip_runtime.h>
#include <hip/hip_bf16.h>
#include <hip/hip_fp16.h>
#include <cstddef>

// ---------------------------------------------------------------------------
// GNN layer (RED-GNN style), MI355X — round 9.
// vs round 8 (487 us, 8-edge unroll caused L2 thrash: FETCH 277->743 MB):
//  * node_kernel reverted to the proven round-7 4-edge structure.
//  * hidden|hsWs packed into ONE fp16 row per node ([node][128] halfs,
//    256 B): halves random-gather bytes and merges two gather streams into
//    one region. fp16 error ~5e-4 — absmax headroom is ~1000x.
// Pipeline: memset(cnt) | fused_pre(matmul->packed fp16 + Br,Cq + hist) |
//           scan x3 | scatter(int2) | node_kernel
// Packing: meta = int2{ (rel<<17)|sub , (e<<8)|r_idx }.
// ---------------------------------------------------------------------------

typedef float    f32x4 __attribute__((ext_vector_type(4)));
typedef _Float16 f16x4 __attribute__((ext_vector_type(4)));

static __device__ __forceinline__ void nt_store4(float* p, float4 v) {
    f32x4 t = {v.x, v.y, v.z, v.w};
    __builtin_nontemporal_store(t, (f32x4*)p);
}
#define NT_STORE(p, v) __builtin_nontemporal_store((v), (p))

// Fused prologue. Block ranges:
//   [0, mmB)        : packed[row] = { fp16(hidden row) | fp16(hidden@Ws row) }
//   [mmB, mmB+relB) : Br = rela@Wr ; Cq = rela[q_rel]@Wqr + b   (fp32)
//   [mmB+relB, ...) : obj histogram + out_obj NT write
__global__ void fused_pre_kernel(const float* __restrict__ hidden,
                                 const float* __restrict__ Ws,
                                 _Float16* __restrict__ packed, int nnode,
                                 const float* __restrict__ rela,
                                 const float* __restrict__ Wr,
                                 const float* __restrict__ Wqr,
                                 const float* __restrict__ Wqr_b,
                                 const int* __restrict__ q_rel,
                                 float* __restrict__ Br,
                                 float* __restrict__ Cq, int nrel, int nq,
                                 const int* __restrict__ edges,
                                 int* __restrict__ cnt_obj,
                                 float* __restrict__ out_obj, int nedge,
                                 int mmB, int relB) {
    __shared__ float W1[64][64];
    __shared__ float W2[64][64];
    int bid = blockIdx.x;
    int tid = threadIdx.x;

    if (bid < mmB) {
        for (int i = tid; i < 4096; i += 256) W1[i >> 6][i & 63] = Ws[i];
        __syncthreads();
        int col = tid & 63, r4 = tid >> 6;
        for (long row = (long)bid * 4 + r4; row < nnode; row += (long)mmB * 4) {
            float xv  = hidden[row * 64 + col];
            float acc = 0.0f;
#pragma unroll
            for (int k = 0; k < 64; ++k)
                acc = fmaf(__shfl(xv, k, 64), W1[k][col], acc);
            packed[row * 128 + col]      = (_Float16)xv;    // hidden row
            packed[row * 128 + 64 + col] = (_Float16)acc;   // hsWs row
        }
    } else if (bid < mmB + relB) {
        for (int i = tid; i < 4096; i += 256) {
            W1[i >> 6][i & 63] = Wr[i];
            W2[i >> 6][i & 63] = Wqr[i];
        }
        __syncthreads();
        int col = tid & 63, r4 = tid >> 6;
        int row = (bid - mmB) * 4 + r4;
        int total = nrel + nq;
        if (row < total) {
            if (row < nrel) {
                float xv  = rela[(size_t)row * 64 + col];
                float acc = 0.0f;
#pragma unroll
                for (int k = 0; k < 64; ++k)
                    acc = fmaf(__shfl(xv, k, 64), W1[k][col], acc);
                Br[(size_t)row * 64 + col] = acc;
            } else {
                int q  = row - nrel;
                int rr = q_rel[q];
                float xv  = rela[(size_t)rr * 64 + col];
                float acc = Wqr_b[col];
#pragma unroll
                for (int k = 0; k < 64; ++k)
                    acc = fmaf(__shfl(xv, k, 64), W2[k][col], acc);
                Cq[(size_t)q * 64 + col] = acc;
            }
        }
    } else {
        int e = (bid - mmB - relB) * 256 + tid;
        if (e < nedge) {
            int obj = edges[(size_t)e * 6 + 5];
            atomicAdd(&cnt_obj[obj], 1);
            NT_STORE(&out_obj[e], (float)obj);
        }
    }
}

// ---- 3-pass exclusive scan over cnt[n], chunk = 1024 ----

__global__ void scan_reduce_kernel(const int* __restrict__ cnt,
                                   int* __restrict__ bsum, int n) {
    int i = blockIdx.x * 1024 + threadIdx.x;
    int v = (i < n) ? cnt[i] : 0;
    int lane = threadIdx.x & 63, w = threadIdx.x >> 6;
#pragma unroll
    for (int m = 1; m < 64; m <<= 1) v += __shfl_xor(v, m, 64);
    __shared__ int ws[16];
    if (lane == 0) ws[w] = v;
    __syncthreads();
    if (threadIdx.x == 0) {
        int s = 0;
#pragma unroll
        for (int k = 0; k < 16; ++k) s += ws[k];
        bsum[blockIdx.x] = s;
    }
}

__global__ void scan_top_kernel(int* __restrict__ bsum, int nb) {
    int tid = threadIdx.x;
    int lane = tid & 63, w = tid >> 6;
    int v = (tid < nb) ? bsum[tid] : 0;
    int ins = v;
#pragma unroll
    for (int off = 1; off < 64; off <<= 1) {
        int t = __shfl_up(ins, off, 64);
        if (lane >= off) ins += t;
    }
    __shared__ int ws[16];
    __shared__ int wo[16];
    if (lane == 63) ws[w] = ins;
    __syncthreads();
    if (tid == 0) {
        int s = 0;
        for (int k = 0; k < 16; ++k) { wo[k] = s; s += ws[k]; }
    }
    __syncthreads();
    if (tid < nb) bsum[tid] = wo[w] + ins - v;   // exclusive
}

__global__ void scan_apply_kernel(const int* __restrict__ cnt,
                                  const int* __restrict__ boffs,
                                  int* __restrict__ out1,
                                  int* __restrict__ out2, int n) {
    int i = blockIdx.x * 1024 + threadIdx.x;
    int lane = threadIdx.x & 63, w = threadIdx.x >> 6;
    int v = (i < n) ? cnt[i] : 0;
    int ins = v;
#pragma unroll
    for (int off = 1; off < 64; off <<= 1) {
        int t = __shfl_up(ins, off, 64);
        if (lane >= off) ins += t;
    }
    __shared__ int ws[16];
    __shared__ int wo[16];
    if (lane == 63) ws[w] = ins;
    __syncthreads();
    if (threadIdx.x == 0) {
        int s = 0;
        for (int k = 0; k < 16; ++k) { wo[k] = s; s += ws[k]; }
    }
    __syncthreads();
    if (i < n) {
        int r = boffs[blockIdx.x] + wo[w] + ins - v;
        out1[i] = r;
        if (out2) out2[i] = r;
    }
}

// Counting-sort scatter: ONE packed int2 write per edge.
__global__ void scatter_kernel(const int* __restrict__ edges,
                               int* __restrict__ cur_obj,
                               int2* __restrict__ meta, int nedge) {
    int e = blockIdx.x * 256 + threadIdx.x;
    if (e >= nedge) return;
    int r_idx = edges[(size_t)e * 6 + 0];
    int rel   = edges[(size_t)e * 6 + 2];
    int sub   = edges[(size_t)e * 6 + 4];
    int obj   = edges[(size_t)e * 6 + 5];
    int p = atomicAdd(&cur_obj[obj], 1);
    meta[p] = make_int2((rel << 17) | sub, (e << 8) | r_idx);
}

// Merged per-node kernel (round-7 4-edge structure, fp16 packed gathers).
// One wave per node; 4 edges/iter, 16 lanes x 4 features each.
__global__ void node_kernel(const int2* __restrict__ meta,
                            const _Float16* __restrict__ packed,
                            const float* __restrict__ rela,
                            const float* __restrict__ Br,
                            const float* __restrict__ Cq,
                            const float* __restrict__ w_alpha_w,
                            const float* __restrict__ w_alpha_b,
                            const int* __restrict__ offs,
                            const int* __restrict__ cnt,
                            const float* __restrict__ Wh,
                            float* __restrict__ out_alpha,
                            float* __restrict__ out_message,
                            float* __restrict__ out_alpha_temp,
                            float* __restrict__ hidden_new,
                            int nnode, int nedge) {
    __shared__ float Wl[64][64];
    int tid = threadIdx.x;
    for (int i = tid; i < 4096; i += 256) Wl[i >> 6][i & 63] = Wh[i];
    __syncthreads();
    int lane = tid & 63;
    int g    = lane >> 4;        // edge slot (0..3)
    int s    = lane & 15;        // feature chunk (4 floats)
    int wv   = tid >> 6;
    const float4 wa = *(const float4*)(w_alpha_w + s * 4);
    const float  wb = w_alpha_b[0];

    for (long node = (long)blockIdx.x * 4 + wv; node < nnode;
         node += (long)gridDim.x * 4) {
        int beg = offs[node];
        int num = cnt[node];
        int end = beg + num;
        float4 acc = make_float4(0.f, 0.f, 0.f, 0.f);

        for (int p0 = beg; p0 < end; p0 += 4) {
            // 4 positions' packed meta = 8 consecutive ints (linear read).
            int mi = 0;
            long mofs = (long)p0 * 2 + lane;
            if (lane < 8 && mofs < (long)nedge * 2)
                mi = ((const int*)meta)[mofs];
            int A = __shfl(mi, g * 2 + 0, 64);
            int B = __shfl(mi, g * 2 + 1, 64);
            bool valid = (p0 + g < end);
            int sub   = A & 0x1FFFF;
            int rel   = (A >> 17) & 0x1FF;
            int r_idx = B & 255;
            long e    = ((unsigned)B) >> 8;
            if (!valid) { sub = 0; rel = 0; r_idx = 0; }

            // one 256 B packed region per edge: hidden half + hsWs half
            const f16x4 hh = *(const f16x4*)(packed + (size_t)sub * 128 + s * 4);
            const f16x4 hw = *(const f16x4*)(packed + (size_t)sub * 128 + 64 + s * 4);
            const float4 b4 = *(const float4*)(Br   + (size_t)rel  * 64 + s * 4);
            const float4 c4 = *(const float4*)(Cq   + (size_t)r_idx* 64 + s * 4);
            const float4 rv = *(const float4*)(rela   + (size_t)rel * 64 + s * 4);

            float4 a4;
            a4.x = fmaxf((float)hw[0] + b4.x + c4.x, 0.0f);
            a4.y = fmaxf((float)hw[1] + b4.y + c4.y, 0.0f);
            a4.z = fmaxf((float)hw[2] + b4.z + c4.z, 0.0f);
            a4.w = fmaxf((float)hw[3] + b4.w + c4.w, 0.0f);

            float part = a4.x * wa.x + a4.y * wa.y + a4.z * wa.z + a4.w * wa.w;
            part += __shfl_xor(part, 1, 64);
            part += __shfl_xor(part, 2, 64);
            part += __shfl_xor(part, 4, 64);
            part += __shfl_xor(part, 8, 64);

            float at    = part + wb;
            float alpha = valid ? 1.0f / (1.0f + __expf(-at)) : 0.0f;

            float4 m4;
            m4.x = alpha * ((float)hh[0] + rv.x);
            m4.y = alpha * ((float)hh[1] + rv.y);
            m4.z = alpha * ((float)hh[2] + rv.z);
            m4.w = alpha * ((float)hh[3] + rv.w);

            acc.x += m4.x; acc.y += m4.y; acc.z += m4.z; acc.w += m4.w;

            if (valid) {
                nt_store4(out_message + e * 64 + s * 4, m4);
                if (s == 0) {
                    out_alpha[e]      = alpha;
                    out_alpha_temp[e] = at;
                }
            }
        }

        // reduce across the 4 groups; all lanes end with the full row sum
        acc.x += __shfl_xor(acc.x, 16, 64); acc.x += __shfl_xor(acc.x, 32, 64);
        acc.y += __shfl_xor(acc.y, 16, 64); acc.y += __shfl_xor(acc.y, 32, 64);
        acc.z += __shfl_xor(acc.z, 16, 64); acc.z += __shfl_xor(acc.z, 32, 64);
        acc.w += __shfl_xor(acc.w, 16, 64); acc.w += __shfl_xor(acc.w, 32, 64);

        // matvec: out[lane] = sum_k x_k * Wl[k][lane]
        float outv = 0.0f;
#pragma unroll
        for (int k = 0; k < 64; ++k) {
            float xk;
            if      ((k & 3) == 0) xk = __shfl(acc.x, k >> 2, 64);
            else if ((k & 3) == 1) xk = __shfl(acc.y, k >> 2, 64);
            else if ((k & 3) == 2) xk = __shfl(acc.z, k >> 2, 64);
            else                   xk = __shfl(acc.w, k >> 2, 64);
            outv = fmaf(xk, Wl[k][lane], outv);
        }
        NT_STORE(&hidden_new[node * 64 + lane], outv);
    }
}

extern "C" void kernel_launch(void* const* d_in, const int* in_sizes, int n_in,
                              void* d_out, int out_size, void* d_ws, size_t ws_size,
                              hipStream_t stream) {
    const int*   q_rel     = (const int*)d_in[1];
    const float* hidden    = (const float*)d_in[2];
    const int*   edges     = (const int*)d_in[3];
    const float* rela      = (const float*)d_in[5];
    const float* Ws        = (const float*)d_in[6];
    const float* Wr        = (const float*)d_in[7];
    const float* Wqr       = (const float*)d_in[8];
    const float* Wqr_b     = (const float*)d_in[9];
    const float* w_alpha_w = (const float*)d_in[10];
    const float* w_alpha_b = (const float*)d_in[11];
    const float* W_h       = (const float*)d_in[12];

    const int n_node = in_sizes[2] / 64;    // 100000
    const int n_edge = in_sizes[3] / 6;     // 1000000
    const int n_rel  = in_sizes[5] / 64;    // 401
    const int n_q    = in_sizes[1];         // 256

    // Output layout (all fp32, return order).
    float* out            = (float*)d_out;
    float* out_hidden_new = out;
    float* out_alpha      = out + (size_t)n_node * 64;
    float* out_message    = out_alpha + n_edge;
    float* out_obj        = out_message + (size_t)n_edge * 64;
    float* out_alpha_temp = out_obj + n_edge;

    // Workspace layout (~36 MB).
    _Float16* packed  = (_Float16*)d_ws;                   // n_node*128 halfs
    float*    Br      = (float*)(packed + (size_t)n_node * 128); // n_rel*64
    float*    Cq      = Br + (size_t)n_rel * 64;           // n_q*64
    int*      cnt_obj = (int*)(Cq + (size_t)n_q * 64);     // n_node
    int*      offs_obj= cnt_obj + n_node;                  // n_node
    int*      cur_obj = offs_obj + n_node;                 // n_node
    int*      bsum    = cur_obj + n_node;                  // 1024
    int2*     meta    = (int2*)(bsum + 1024);              // n_edge int2 (8 MB)

    const int nb = (n_node + 1023) / 1024;                 // scan blocks (98)

    (void)hipMemsetAsync(cnt_obj, 0, (size_t)n_node * sizeof(int), stream);

    // 1) fused prologue: packed fp16 table | Br,Cq | obj hist + out_obj
    const int mmB   = 2048;
    const int relB  = (n_rel + n_q + 3) / 4;
    const int histB = (n_edge + 255) / 256;
    fused_pre_kernel<<<mmB + relB + histB, 256, 0, stream>>>(
        hidden, Ws, packed, n_node,
        rela, Wr, Wqr, Wqr_b, q_rel, Br, Cq, n_rel, n_q,
        edges, cnt_obj, out_obj, n_edge, mmB, relB);

    // 2) exclusive scan: cnt_obj -> offs_obj (+ cur_obj cursor copy)
    scan_reduce_kernel<<<nb, 1024, 0, stream>>>(cnt_obj, bsum, n_node);
    scan_top_kernel<<<1, 1024, 0, stream>>>(bsum, nb);
    scan_apply_kernel<<<nb, 1024, 0, stream>>>(cnt_obj, bsum, offs_obj,
                                               cur_obj, n_node);

    // 3) counting-sort scatter (one int2 per edge)
    scatter_kernel<<<(n_edge + 255) / 256, 256, 0, stream>>>(edges, cur_obj,
                                                             meta, n_edge);

    // 4) merged per-node kernel: per-edge compute + aggregate + @W_h
    node_kernel<<<4096, 256, 0, stream>>>(meta, packed, rela, Br, Cq,
                                          w_alpha_w, w_alpha_b,
                                          offs_obj, cnt_obj, W_h,
                                          out_alpha, out_message,
                                          out_alpha_temp, out_hidden_new,
                                          n_node, n_edge);
}